// Round 9
// baseline (901.402 us; speedup 1.0000x reference)
//
#include <hip/hip_runtime.h>
#include <cstdint>
#include <cstddef>

#define M_ROWS 65536
#define N_COLS 1024
#define K_DIM  1024

typedef _Float16 f16x8 __attribute__((ext_vector_type(8)));
typedef float f32x4 __attribute__((ext_vector_type(4)));

// ---------------- prep: scale/bias ----------------
__global__ __launch_bounds__(256) void prep_scale_bias(
    const float* __restrict__ gamma, const float* __restrict__ beta,
    const float* __restrict__ mean, const float* __restrict__ var,
    float* __restrict__ bias, float* __restrict__ scale)
{
  int i = blockIdx.x * 256 + threadIdx.x;
  if (i < N_COLS) {
    float s = gamma[i] * rsqrtf(var[i] + 1e-3f);
    scale[i] = s;
    bias[i] = beta[i] - mean[i] * s;
  }
}

// ---------------- prep: W -> Bp (scaled f16, fragment-permuted, 8-wave geometry) ----
// 16B chunk index = (kt*512 + tid)*16 + kc*8 + fn, tid = wn*64 + g*16 + li (wn in [0,8)),
// holding Wt[n = wn*128 + fn*16 + li][k = kt*64 + kc*32 + g*8 .. +8].
// => lane's 16 fragments for one kt are contiguous 256B at Bp + tid*256 + kt*131072.
__global__ __launch_bounds__(256) void prep_bp(
    const float* __restrict__ W, const float* __restrict__ scale,
    char* __restrict__ Bp)
{
  __shared__ float tile[64][68];
  int k0 = blockIdx.x * 64, n0 = blockIdx.y * 64;
  int t = threadIdx.x;
  int kr = t >> 2, q = t & 3;
  #pragma unroll
  for (int j = 0; j < 4; ++j) {
    float4 v = *(const float4*)(W + (size_t)(k0 + kr) * N_COLS + n0 + q * 16 + j * 4);
    *(float4*)(&tile[kr][q * 16 + j * 4]) = v;
  }
  __syncthreads();
  int nr = t >> 2;
  int n = n0 + nr;
  float sn = scale[n];
  __align__(16) _Float16 h[16];
  #pragma unroll
  for (int j = 0; j < 16; ++j)
    h[j] = (_Float16)(tile[q * 16 + j][nr] * sn);   // h[j] = Wt[n][k0+q*16+j]
  int wn = n >> 7, fn = (n >> 4) & 7, li = n & 15;
  #pragma unroll
  for (int c = 0; c < 2; ++c) {
    int k = k0 + q * 16 + c * 8;
    int kidx = k >> 3;
    int g = kidx & 3, kc = (kidx >> 2) & 1, kt = kidx >> 3;
    int tg = wn * 64 + g * 16 + li;
    size_t chunk = ((size_t)(kt * 512 + tg)) * 16 + kc * 8 + fn;
    *(uint4*)(Bp + chunk * 16) = *(const uint4*)(&h[c * 8]);
  }
}

// ---------------- prep: A (fp32) -> Af (f16), grid-stride, vectorized ----------------
__global__ __launch_bounds__(256) void conv_a_f16(
    const float* __restrict__ A, _Float16* __restrict__ Af)
{
  const size_t total8 = (size_t)M_ROWS * K_DIM / 8;
  size_t i = (size_t)blockIdx.x * 256 + threadIdx.x;
  const size_t stride = (size_t)gridDim.x * 256;
  for (; i < total8; i += stride) {
    float4 a = *(const float4*)(A + i * 8);
    float4 b = *(const float4*)(A + i * 8 + 4);
    union { _Float16 h[8]; uint4 u; } p;
    p.h[0] = (_Float16)a.x; p.h[1] = (_Float16)a.y;
    p.h[2] = (_Float16)a.z; p.h[3] = (_Float16)a.w;
    p.h[4] = (_Float16)b.x; p.h[5] = (_Float16)b.y;
    p.h[6] = (_Float16)b.z; p.h[7] = (_Float16)b.w;
    *(uint4*)(Af + i * 8) = p.u;
  }
}

// ---------------- fused: z = (Af @ W~ + bias) * priors ; out = sparsemax(z) ----------------
// 512 threads = 8 waves; block = 32 rows x 1024 cols; wave wn owns 128-col band.
// Register-sized to FIT: acc[2][8]=64 + bf 4-wide batches (16) + af 8 + addr ~20 => ~110
// under the 128-reg cap of __launch_bounds__(512,4) (4 waves/EU, 2 blocks/CU).
// A: f16 via global_load_lds (waves 0-3), 2 buffers, one __syncthreads per kt (proven R2 loop).
// B: L2-resident permuted Bp, one per-lane base, small immediate offsets.
__global__ __launch_bounds__(512, 4) void fused_gemm_sparsemax(
    const _Float16* __restrict__ Af, const char* __restrict__ Bp,
    const float* __restrict__ bias, const float* __restrict__ priors,
    float* __restrict__ out)
{
  __shared__ char asmem[8192];           // 2 x (32 rows x 64 k x f16)
  __shared__ float red[2][32][9];        // per-row per-wave partials (pad 9: bank-clean)
  __shared__ float redk[2][32][9];

  const int tid = threadIdx.x;
  const int lane = tid & 63, wn = tid >> 6;
  const int li = lane & 15, g = lane >> 4;
  const int m0 = blockIdx.x * 32;

  f32x4 acc[2][8];
  #pragma unroll
  for (int fm = 0; fm < 2; ++fm)
    #pragma unroll
    for (int fn = 0; fn < 8; ++fn) acc[fm][fn] = (f32x4){0.f, 0.f, 0.f, 0.f};

  // ---- A staging: waves 0-3 cover 32x64 f16 tile (256 x 16B chunks) ----
  const int rl = tid >> 3, c8 = tid & 7;   // valid for tid<256
  const char* asrc = (const char*)(Af + (size_t)(m0 + (rl & 31)) * K_DIM)
                     + ((c8 * 16) ^ ((rl & 7) << 4));   // inverse-swizzled source (rule 21)
  auto stageA = [&](int kt, int buf) {
    if (tid < 256)
      __builtin_amdgcn_global_load_lds(
          (const __attribute__((address_space(1))) unsigned int*)(asrc + kt * 128),
          (__attribute__((address_space(3))) unsigned int*)(&asmem[buf * 4096 + tid * 16]),
          16, 0, 0);
  };

  const char* bkt = Bp + (size_t)tid * 256;
  const int aswz = (li & 7) << 4;

  stageA(0, 0);
  __syncthreads();

  for (int kt = 0; kt < 16; ++kt) {
    const int cur = kt & 1;
    if (kt < 15) stageA(kt + 1, cur ^ 1);
    const int abase = cur * 4096;
    #pragma unroll
    for (int kc = 0; kc < 2; ++kc) {
      const int koff = kc * 64 + g * 16;
      f16x8 af0 = *(const f16x8*)(&asmem[abase + li * 128 + (koff ^ aswz)]);
      f16x8 af1 = *(const f16x8*)(&asmem[abase + (16 + li) * 128 + (koff ^ aswz)]);
      // two 4-fragment B batches to bound register pressure
      #pragma unroll
      for (int h = 0; h < 2; ++h) {
        f16x8 bf0 = *(const f16x8*)(bkt + kc * 128 + h * 64);
        f16x8 bf1 = *(const f16x8*)(bkt + kc * 128 + h * 64 + 16);
        f16x8 bf2 = *(const f16x8*)(bkt + kc * 128 + h * 64 + 32);
        f16x8 bf3 = *(const f16x8*)(bkt + kc * 128 + h * 64 + 48);
        acc[0][h * 4 + 0] = __builtin_amdgcn_mfma_f32_16x16x32_f16(af0, bf0, acc[0][h * 4 + 0], 0, 0, 0);
        acc[1][h * 4 + 0] = __builtin_amdgcn_mfma_f32_16x16x32_f16(af1, bf0, acc[1][h * 4 + 0], 0, 0, 0);
        acc[0][h * 4 + 1] = __builtin_amdgcn_mfma_f32_16x16x32_f16(af0, bf1, acc[0][h * 4 + 1], 0, 0, 0);
        acc[1][h * 4 + 1] = __builtin_amdgcn_mfma_f32_16x16x32_f16(af1, bf1, acc[1][h * 4 + 1], 0, 0, 0);
        acc[0][h * 4 + 2] = __builtin_amdgcn_mfma_f32_16x16x32_f16(af0, bf2, acc[0][h * 4 + 2], 0, 0, 0);
        acc[1][h * 4 + 2] = __builtin_amdgcn_mfma_f32_16x16x32_f16(af1, bf2, acc[1][h * 4 + 2], 0, 0, 0);
        acc[0][h * 4 + 3] = __builtin_amdgcn_mfma_f32_16x16x32_f16(af0, bf3, acc[0][h * 4 + 3], 0, 0, 0);
        acc[1][h * 4 + 3] = __builtin_amdgcn_mfma_f32_16x16x32_f16(af1, bf3, acc[1][h * 4 + 3], 0, 0, 0);
      }
    }
    bkt += 131072;
    __syncthreads();   // drains stage(kt+1); guards LDS buffer reuse
  }

  // ---- epilogue: z = (acc + bias) * priors, in registers ----
  {
    float bv[8];
    #pragma unroll
    for (int fn = 0; fn < 8; ++fn) bv[fn] = bias[wn * 128 + fn * 16 + li];
    #pragma unroll
    for (int fm = 0; fm < 2; ++fm)
      #pragma unroll
      for (int r = 0; r < 4; ++r) {
        const float* pp = priors + (size_t)(m0 + fm * 16 + g * 4 + r) * N_COLS + wn * 128 + li;
        #pragma unroll
        for (int fn = 0; fn < 8; ++fn)
          acc[fm][fn][r] = (acc[fm][fn][r] + bv[fn]) * pp[fn * 16];
      }
  }

  // ---- sparsemax (proven 12-bisection + 2-Newton scheme), 8-band combine ----
  float lo[2][4], hi[2][4];
  {
    float mx[2][4];
    #pragma unroll
    for (int fm = 0; fm < 2; ++fm)
      #pragma unroll
      for (int r = 0; r < 4; ++r) {
        float m = acc[fm][0][r];
        #pragma unroll
        for (int fn = 1; fn < 8; ++fn) m = fmaxf(m, acc[fm][fn][r]);
        m = fmaxf(m, __shfl_xor(m, 1, 64));
        m = fmaxf(m, __shfl_xor(m, 2, 64));
        m = fmaxf(m, __shfl_xor(m, 4, 64));
        m = fmaxf(m, __shfl_xor(m, 8, 64));
        mx[fm][r] = m;
      }
    if (li == 0) {
      #pragma unroll
      for (int fm = 0; fm < 2; ++fm)
        #pragma unroll
        for (int r = 0; r < 4; ++r)
          red[0][fm * 16 + g * 4 + r][wn] = mx[fm][r];
    }
    __syncthreads();
    #pragma unroll
    for (int fm = 0; fm < 2; ++fm)
      #pragma unroll
      for (int r = 0; r < 4; ++r) {
        const float* rr = &red[0][fm * 16 + g * 4 + r][0];
        float M = rr[0];
        #pragma unroll
        for (int j = 1; j < 8; ++j) M = fmaxf(M, rr[j]);
        lo[fm][r] = M - 1.0f;
        hi[fm][r] = M;
      }
  }

  float tt[2][4];
  for (int it = 0; it < 12; ++it) {
    const int b = (it + 1) & 1;
    float sv[2][4];
    #pragma unroll
    for (int fm = 0; fm < 2; ++fm)
      #pragma unroll
      for (int r = 0; r < 4; ++r) {
        float t = 0.5f * (lo[fm][r] + hi[fm][r]);
        tt[fm][r] = t;
        float s = 0.f;
        #pragma unroll
        for (int fn = 0; fn < 8; ++fn) s += fmaxf(acc[fm][fn][r] - t, 0.f);
        s += __shfl_xor(s, 1, 64);
        s += __shfl_xor(s, 2, 64);
        s += __shfl_xor(s, 4, 64);
        s += __shfl_xor(s, 8, 64);
        sv[fm][r] = s;
      }
    if (li == 0) {
      #pragma unroll
      for (int fm = 0; fm < 2; ++fm)
        #pragma unroll
        for (int r = 0; r < 4; ++r)
          red[b][fm * 16 + g * 4 + r][wn] = sv[fm][r];
    }
    __syncthreads();
    #pragma unroll
    for (int fm = 0; fm < 2; ++fm)
      #pragma unroll
      for (int r = 0; r < 4; ++r) {
        const float* rr = &red[b][fm * 16 + g * 4 + r][0];
        float S = ((rr[0] + rr[1]) + (rr[2] + rr[3])) + ((rr[4] + rr[5]) + (rr[6] + rr[7]));
        if (S >= 1.f) lo[fm][r] = tt[fm][r]; else hi[fm][r] = tt[fm][r];
      }
  }

  float tv[2][4];
  #pragma unroll
  for (int fm = 0; fm < 2; ++fm)
    #pragma unroll
    for (int r = 0; r < 4; ++r) tv[fm][r] = lo[fm][r];

  for (int nit = 0; nit < 2; ++nit) {
    const int b = (nit + 1) & 1;
    float sv[2][4], kv[2][4];
    #pragma unroll
    for (int fm = 0; fm < 2; ++fm)
      #pragma unroll
      for (int r = 0; r < 4; ++r) {
        float s = 0.f, k = 0.f;
        float t = tv[fm][r];
        #pragma unroll
        for (int fn = 0; fn < 8; ++fn) {
          float d = acc[fm][fn][r];
          bool gt = d > t;
          s += gt ? d : 0.f;
          k += gt ? 1.f : 0.f;
        }
        s += __shfl_xor(s, 1, 64); k += __shfl_xor(k, 1, 64);
        s += __shfl_xor(s, 2, 64); k += __shfl_xor(k, 2, 64);
        s += __shfl_xor(s, 4, 64); k += __shfl_xor(k, 4, 64);
        s += __shfl_xor(s, 8, 64); k += __shfl_xor(k, 8, 64);
        sv[fm][r] = s; kv[fm][r] = k;
      }
    if (li == 0) {
      #pragma unroll
      for (int fm = 0; fm < 2; ++fm)
        #pragma unroll
        for (int r = 0; r < 4; ++r) {
          red[b][fm * 16 + g * 4 + r][wn] = sv[fm][r];
          redk[b][fm * 16 + g * 4 + r][wn] = kv[fm][r];
        }
    }
    __syncthreads();
    #pragma unroll
    for (int fm = 0; fm < 2; ++fm)
      #pragma unroll
      for (int r = 0; r < 4; ++r) {
        const float* rr = &red[b][fm * 16 + g * 4 + r][0];
        const float* rk = &redk[b][fm * 16 + g * 4 + r][0];
        float S = 0.f, K = 0.f;
        #pragma unroll
        for (int j = 0; j < 8; ++j) { S += rr[j]; K += rk[j]; }
        tv[fm][r] = (S - 1.f) / K;   // K >= 1 (row max stays in support)
      }
  }

  #pragma unroll
  for (int fm = 0; fm < 2; ++fm)
    #pragma unroll
    for (int r = 0; r < 4; ++r) {
      float* op = out + (size_t)(m0 + fm * 16 + g * 4 + r) * N_COLS + wn * 128 + li;
      float t = tv[fm][r];
      #pragma unroll
      for (int fn = 0; fn < 8; ++fn)
        op[fn * 16] = fmaxf(acc[fm][fn][r] - t, 0.f);
    }
}

// ---------------- FALLBACK path (ws too small): R2 split kernels ----------------
__global__ __launch_bounds__(256) void prep_wt(
    const float* __restrict__ W, const float* __restrict__ scale,
    _Float16* __restrict__ Wt)
{
  __shared__ float tile[64][68];
  int k0 = blockIdx.x * 64, n0 = blockIdx.y * 64;
  int t = threadIdx.x;
  int kr = t >> 2, q = t & 3;
  #pragma unroll
  for (int j = 0; j < 4; ++j) {
    float4 v = *(const float4*)(W + (size_t)(k0 + kr) * N_COLS + n0 + q * 16 + j * 4);
    *(float4*)(&tile[kr][q * 16 + j * 4]) = v;
  }
  __syncthreads();
  int nr = t >> 2;
  float sn = scale[n0 + nr];
  __align__(16) _Float16 h[16];
  #pragma unroll
  for (int j = 0; j < 16; ++j)
    h[j] = (_Float16)(tile[q * 16 + j][nr] * sn);
  uint4* dst = (uint4*)(Wt + (size_t)(n0 + nr) * K_DIM + k0 + q * 16);
  dst[0] = *(uint4*)(&h[0]);
  dst[1] = *(uint4*)(&h[8]);
}

__global__ __launch_bounds__(256, 2) void gemm_f16(
    const float* __restrict__ A, const _Float16* __restrict__ Wt,
    const float* __restrict__ bias, const float* __restrict__ priors,
    float* __restrict__ out)
{
  __shared__ char smem[65536];
  const int tid = threadIdx.x;
  const int lane = tid & 63, wid = tid >> 6;
  const int wm = wid >> 1, wnn = wid & 1;
  int orig = blockIdx.x;
  int wgid = (orig & 7) * 512 + (orig >> 3);
  int mb = wgid >> 3, nb = wgid & 7;
  const int m0 = mb * 128, n0 = nb * 128;
  f32x4 acc[4][4];
  #pragma unroll
  for (int i = 0; i < 4; ++i)
    #pragma unroll
    for (int j = 0; j < 4; ++j) acc[i][j] = (f32x4){0.f, 0.f, 0.f, 0.f};
  float4 areg[8];
  auto loadA = [&](int kt) {
    #pragma unroll
    for (int j = 0; j < 8; ++j) {
      int f = j * 256 + tid;
      int ml = f >> 4, k4 = (f & 15) << 2;
      areg[j] = *(const float4*)(A + (size_t)(m0 + ml) * K_DIM + kt * 64 + k4);
    }
  };
  auto storeA = [&](int buf) {
    int base = buf * 16384;
    #pragma unroll
    for (int j = 0; j < 8; ++j) {
      int f = j * 256 + tid;
      int ml = f >> 4, k4 = (f & 15) << 2;
      int off = ml * 128 + ((k4 * 2) ^ ((ml & 7) << 4));
      union { _Float16 h[4]; uint2 u; } p;
      p.h[0] = (_Float16)areg[j].x; p.h[1] = (_Float16)areg[j].y;
      p.h[2] = (_Float16)areg[j].z; p.h[3] = (_Float16)areg[j].w;
      *(uint2*)(&smem[base + off]) = p.u;
    }
  };
  auto issueB = [&](int kt, int buf) {
    int base = 32768 + buf * 16384;
    #pragma unroll
    for (int t4 = 0; t4 < 4; ++t4) {
      int ch = t4 * 256 + tid;
      int nl = ch >> 3, c = ch & 7;
      const char* src = (const char*)Wt + ((size_t)(n0 + nl) * K_DIM + kt * 64) * 2
          + ((c * 16) ^ ((nl & 7) << 4));
      __builtin_amdgcn_global_load_lds(
          (const __attribute__((address_space(1))) unsigned int*)src,
          (__attribute__((address_space(3))) unsigned int*)(&smem[base + ch * 16]),
          16, 0, 0);
    }
  };
  loadA(0); issueB(0, 0); storeA(0);
  __syncthreads();
  for (int kt = 0; kt < 16; ++kt) {
    int curb = kt & 1, nxt = curb ^ 1;
    if (kt < 15) { loadA(kt + 1); issueB(kt + 1, nxt); }
    int ab = curb * 16384, bb = 32768 + curb * 16384;
    #pragma unroll
    for (int kc = 0; kc < 2; ++kc) {
      int k2 = (kc * 32 + ((lane >> 4) * 8)) * 2;
      f16x8 af[4], bfr[4];
      #pragma unroll
      for (int fm = 0; fm < 4; ++fm) {
        int rl2 = wm * 64 + fm * 16 + (lane & 15);
        af[fm] = *(const f16x8*)(&smem[ab + rl2 * 128 + (k2 ^ ((rl2 & 7) << 4))]);
      }
      #pragma unroll
      for (int fn = 0; fn < 4; ++fn) {
        int nl = wnn * 64 + fn * 16 + (lane & 15);
        bfr[fn] = *(const f16x8*)(&smem[bb + nl * 128 + (k2 ^ ((nl & 7) << 4))]);
      }
      #pragma unroll
      for (int fm = 0; fm < 4; ++fm)
        #pragma unroll
        for (int fn = 0; fn < 4; ++fn)
          acc[fm][fn] = __builtin_amdgcn_mfma_f32_16x16x32_f16(af[fm], bfr[fn], acc[fm][fn], 0, 0, 0);
    }
    if (kt < 15) storeA(nxt);
    __syncthreads();
  }
  #pragma unroll
  for (int fn = 0; fn < 4; ++fn) {
    int col = n0 + wnn * 64 + fn * 16 + (lane & 15);
    float bvv = bias[col];
    #pragma unroll
    for (int fm = 0; fm < 4; ++fm) {
      int row0 = m0 + wm * 64 + fm * 16 + ((lane >> 4) << 2);
      #pragma unroll
      for (int r = 0; r < 4; ++r) {
        size_t idx = (size_t)(row0 + r) * N_COLS + col;
        out[idx] = (acc[fm][fn][r] + bvv) * priors[idx];
      }
    }
  }
}

__global__ __launch_bounds__(256) void sparsemax_rows(float* __restrict__ z)
{
  const int lane = threadIdx.x & 63, wid = threadIdx.x >> 6;
  const size_t row = (size_t)blockIdx.x * 4 + wid;
  float* p = z + row * N_COLS;
  float v[16];
  #pragma unroll
  for (int j = 0; j < 4; ++j) {
    float4 t = *(const float4*)(p + j * 256 + lane * 4);
    v[j * 4 + 0] = t.x; v[j * 4 + 1] = t.y; v[j * 4 + 2] = t.z; v[j * 4 + 3] = t.w;
  }
  float mx = v[0];
  #pragma unroll
  for (int j = 1; j < 16; ++j) mx = fmaxf(mx, v[j]);
  #pragma unroll
  for (int m = 1; m <= 32; m <<= 1) mx = fmaxf(mx, __shfl_xor(mx, m, 64));
  float lo = mx - 1.0f, hi = mx;
  for (int it = 0; it < 12; ++it) {
    float tau = 0.5f * (lo + hi);
    float s = 0.f;
    #pragma unroll
    for (int j = 0; j < 16; ++j) s += fmaxf(v[j] - tau, 0.f);
    #pragma unroll
    for (int m = 1; m <= 32; m <<= 1) s += __shfl_xor(s, m, 64);
    if (s >= 1.f) lo = tau; else hi = tau;
  }
  float tau = lo;
  #pragma unroll
  for (int it = 0; it < 2; ++it) {
    float s = 0.f, k = 0.f;
    #pragma unroll
    for (int j = 0; j < 16; ++j) {
      bool gg = v[j] > tau;
      s += gg ? v[j] : 0.f;
      k += gg ? 1.f : 0.f;
    }
    #pragma unroll
    for (int m = 1; m <= 32; m <<= 1) { s += __shfl_xor(s, m, 64); k += __shfl_xor(k, m, 64); }
    tau = (s - 1.f) / k;
  }
  #pragma unroll
  for (int j = 0; j < 4; ++j) {
    float4 t;
    t.x = fmaxf(v[j * 4 + 0] - tau, 0.f);
    t.y = fmaxf(v[j * 4 + 1] - tau, 0.f);
    t.z = fmaxf(v[j * 4 + 2] - tau, 0.f);
    t.w = fmaxf(v[j * 4 + 3] - tau, 0.f);
    *(float4*)(p + j * 256 + lane * 4) = t;
  }
}

// ---------------- launch ----------------
extern "C" void kernel_launch(void* const* d_in, const int* in_sizes, int n_in,
                              void* d_out, int out_size, void* d_ws, size_t ws_size,
                              hipStream_t stream) {
  const float* inputs = (const float*)d_in[0];
  const float* priors = (const float*)d_in[1];
  const float* W      = (const float*)d_in[2];
  const float* gamma  = (const float*)d_in[3];
  const float* beta   = (const float*)d_in[4];
  const float* mean   = (const float*)d_in[5];
  const float* var    = (const float*)d_in[6];
  float* out = (float*)d_out;

  char* ws = (char*)d_ws;
  float* bias  = (float*)ws;                 // 4 KB
  float* scale = (float*)(ws + 4096);        // 4 KB
  char*  Bp    = ws + 8192;                  // 2 MB (fragment-permuted) or Wt (fallback)
  const size_t AF_OFF = 8192 + (size_t)N_COLS * K_DIM * 2;
  _Float16* Af = (_Float16*)(ws + AF_OFF);   // 134 MB, [M][K] f16
  const size_t need = AF_OFF + (size_t)M_ROWS * K_DIM * 2;

  prep_scale_bias<<<4, 256, 0, stream>>>(gamma, beta, mean, var, bias, scale);

  if (ws_size >= need) {
    prep_bp<<<dim3(16, 16), 256, 0, stream>>>(W, scale, Bp);
    conv_a_f16<<<2048, 256, 0, stream>>>(inputs, Af);
    fused_gemm_sparsemax<<<M_ROWS / 32, 512, 0, stream>>>(Af, Bp, bias, priors, out);
  } else {
    prep_wt<<<dim3(16, 16), 256, 0, stream>>>(W, scale, (_Float16*)Bp);
    gemm_f16<<<4096, 256, 0, stream>>>(inputs, (_Float16*)Bp, bias, priors, out);
    sparsemax_rows<<<16384, 256, 0, stream>>>(out);
  }
}

// Round 10
// 411.286 us; speedup vs baseline: 2.1917x; 2.1917x over previous
//
#include <hip/hip_runtime.h>
#include <cstdint>
#include <cstddef>

#define M_ROWS 65536
#define N_COLS 1024
#define K_DIM  1024

typedef _Float16 f16x8 __attribute__((ext_vector_type(8)));
typedef float f32x4 __attribute__((ext_vector_type(4)));

// ---------------- prep: scale/bias ----------------
__global__ __launch_bounds__(256) void prep_scale_bias(
    const float* __restrict__ gamma, const float* __restrict__ beta,
    const float* __restrict__ mean, const float* __restrict__ var,
    float* __restrict__ bias, float* __restrict__ scale)
{
  int i = blockIdx.x * 256 + threadIdx.x;
  if (i < N_COLS) {
    float s = gamma[i] * rsqrtf(var[i] + 1e-3f);
    scale[i] = s;
    bias[i] = beta[i] - mean[i] * s;
  }
}

// ---------------- prep: W -> Wt (transposed, scaled, f16) ----------------
__global__ __launch_bounds__(256) void prep_wt(
    const float* __restrict__ W, const float* __restrict__ scale,
    _Float16* __restrict__ Wt)
{
  __shared__ float tile[64][68];
  int k0 = blockIdx.x * 64, n0 = blockIdx.y * 64;
  int t = threadIdx.x;
  int kr = t >> 2, q = t & 3;
  #pragma unroll
  for (int j = 0; j < 4; ++j) {
    float4 v = *(const float4*)(W + (size_t)(k0 + kr) * N_COLS + n0 + q * 16 + j * 4);
    *(float4*)(&tile[kr][q * 16 + j * 4]) = v;
  }
  __syncthreads();
  int nr = t >> 2;
  float sn = scale[n0 + nr];
  __align__(16) _Float16 h[16];
  #pragma unroll
  for (int j = 0; j < 16; ++j)
    h[j] = (_Float16)(tile[q * 16 + j][nr] * sn);
  uint4* dst = (uint4*)(Wt + (size_t)(n0 + nr) * K_DIM + k0 + q * 16);
  dst[0] = *(uint4*)(&h[0]);
  dst[1] = *(uint4*)(&h[8]);
}

// ---------------- prep: A (fp32) -> Af (f16), grid-stride, vectorized ----------------
__global__ __launch_bounds__(256) void conv_a_f16(
    const float* __restrict__ A, _Float16* __restrict__ Af)
{
  const size_t total8 = (size_t)M_ROWS * K_DIM / 8;
  size_t i = (size_t)blockIdx.x * 256 + threadIdx.x;
  const size_t stride = (size_t)gridDim.x * 256;
  for (; i < total8; i += stride) {
    float4 a = *(const float4*)(A + i * 8);
    float4 b = *(const float4*)(A + i * 8 + 4);
    union { _Float16 h[8]; uint4 u; } p;
    p.h[0] = (_Float16)a.x; p.h[1] = (_Float16)a.y;
    p.h[2] = (_Float16)a.z; p.h[3] = (_Float16)a.w;
    p.h[4] = (_Float16)b.x; p.h[5] = (_Float16)b.y;
    p.h[6] = (_Float16)b.z; p.h[7] = (_Float16)b.w;
    *(uint4*)(Af + i * 8) = p.u;
  }
}

// ---------------- GEMM with counted-vmcnt pipeline (T4, m139 pattern) ----------------
// 128x128 tile, BK=64, 4 waves, dbuf LDS (64KB). Prologue stages kt0+kt1 (16 loads).
// Loop top: vmcnt(8) + s_barrier  -> stage(kt) complete, stage(kt+1) stays in flight.
// Loop end: lgkmcnt(0) + s_barrier -> all reads retired; then stage(kt+2) into freed buf.
// F16OUT=1: write z as f16 into zout (half traffic); F16OUT=0: f32 (exact R2 epilogue).
template<int F16OUT>
__global__ __launch_bounds__(256, 2) void gemm_cnt(
    const _Float16* __restrict__ Af, const _Float16* __restrict__ Wt,
    const float* __restrict__ bias, const float* __restrict__ priors,
    void* __restrict__ zout)
{
  __shared__ char smem[65536];  // A0 @0, A1 @16384, B0 @32768, B1 @49152
  const int tid = threadIdx.x;
  const int lane = tid & 63, wid = tid >> 6;
  const int wm = wid >> 1, wn = wid & 1;

  // bijective XCD swizzle (nwg=4096, 4096%8==0)
  int orig = blockIdx.x;
  int wgid = (orig & 7) * 512 + (orig >> 3);
  int mb = wgid >> 3, nb = wgid & 7;
  const int m0 = mb * 128, n0 = nb * 128;

  f32x4 acc[4][4];
  #pragma unroll
  for (int i = 0; i < 4; ++i)
    #pragma unroll
    for (int j = 0; j < 4; ++j) acc[i][j] = (f32x4){0.f, 0.f, 0.f, 0.f};

  // stage one 128x64 f16 tile (16KB): linear LDS dest + inverse-swizzled global src (rule 21)
  auto issueTile = [&](const _Float16* base, int rowBase, int kt, int ldsOff) {
    #pragma unroll
    for (int t4 = 0; t4 < 4; ++t4) {
      int ch = t4 * 256 + tid;     // 16B chunk index, 1024 chunks
      int rl = ch >> 3, c = ch & 7;
      const char* src = (const char*)base
          + ((size_t)(rowBase + rl) * K_DIM + kt * 64) * 2
          + ((c * 16) ^ ((rl & 7) << 4));
      __builtin_amdgcn_global_load_lds(
          (const __attribute__((address_space(1))) unsigned int*)src,
          (__attribute__((address_space(3))) unsigned int*)(&smem[ldsOff + ch * 16]),
          16, 0, 0);
    }
  };

  // prologue: stage kt0 and kt1 (16 loads in flight; 8 per stage per thread-wave)
  issueTile(Af, m0, 0, 0);
  issueTile(Wt, n0, 0, 32768);
  issueTile(Af, m0, 1, 16384);
  issueTile(Wt, n0, 1, 49152);

  for (int kt = 0; kt < 16; ++kt) {
    // wait for stage(kt): 8 newer ops (stage kt+1) may remain in flight
    if (kt < 15) asm volatile("s_waitcnt vmcnt(8)" ::: "memory");
    else         asm volatile("s_waitcnt vmcnt(0)" ::: "memory");
    __builtin_amdgcn_s_barrier();
    asm volatile("" ::: "memory");
    __builtin_amdgcn_sched_barrier(0);

    const int cur = kt & 1;
    const int ab = cur * 16384, bb = 32768 + cur * 16384;
    #pragma unroll
    for (int kc = 0; kc < 2; ++kc) {
      int k2 = (kc * 32 + ((lane >> 4) * 8)) * 2;
      f16x8 af[4], bf[4];
      #pragma unroll
      for (int fm = 0; fm < 4; ++fm) {
        int rl = wm * 64 + fm * 16 + (lane & 15);
        af[fm] = *(const f16x8*)(&smem[ab + rl * 128 + (k2 ^ ((rl & 7) << 4))]);
      }
      #pragma unroll
      for (int fn = 0; fn < 4; ++fn) {
        int nl = wn * 64 + fn * 16 + (lane & 15);
        bf[fn] = *(const f16x8*)(&smem[bb + nl * 128 + (k2 ^ ((nl & 7) << 4))]);
      }
      #pragma unroll
      for (int fm = 0; fm < 4; ++fm)
        #pragma unroll
        for (int fn = 0; fn < 4; ++fn)
          acc[fm][fn] = __builtin_amdgcn_mfma_f32_16x16x32_f16(af[fm], bf[fn], acc[fm][fn], 0, 0, 0);
    }

    // all my LDS reads retired; barrier so every wave is done with buf[cur]
    asm volatile("s_waitcnt lgkmcnt(0)" ::: "memory");
    __builtin_amdgcn_s_barrier();
    asm volatile("" ::: "memory");
    __builtin_amdgcn_sched_barrier(0);
    // refill the just-freed buffer with stage(kt+2)
    if (kt < 14) {
      issueTile(Af, m0, kt + 2, ab);
      issueTile(Wt, n0, kt + 2, bb);
    }
  }

  // epilogue: z = (acc + bias) * priors
  #pragma unroll
  for (int fn = 0; fn < 4; ++fn) {
    int col = n0 + wn * 64 + fn * 16 + (lane & 15);
    float bv = bias[col];
    #pragma unroll
    for (int fm = 0; fm < 4; ++fm) {
      int row0 = m0 + wm * 64 + fm * 16 + ((lane >> 4) << 2);
      #pragma unroll
      for (int r = 0; r < 4; ++r) {
        size_t idx = (size_t)(row0 + r) * N_COLS + col;
        float z = (acc[fm][fn][r] + bv) * priors[idx];
        if (F16OUT) ((_Float16*)zout)[idx] = (_Float16)z;
        else        ((float*)zout)[idx] = z;
      }
    }
  }
}

// ---------------- sparsemax from f16 z -> f32 out, one wave per row ----------------
__global__ __launch_bounds__(256) void sparsemax_rows_h(
    const _Float16* __restrict__ zh, float* __restrict__ outp)
{
  const int lane = threadIdx.x & 63, wid = threadIdx.x >> 6;
  const size_t row = (size_t)blockIdx.x * 4 + wid;
  const _Float16* p = zh + row * N_COLS + lane * 16;

  f16x8 h0 = *(const f16x8*)(p);
  f16x8 h1 = *(const f16x8*)(p + 8);
  float v[16];
  #pragma unroll
  for (int j = 0; j < 8; ++j) { v[j] = (float)h0[j]; v[8 + j] = (float)h1[j]; }

  float mx = v[0];
  #pragma unroll
  for (int j = 1; j < 16; ++j) mx = fmaxf(mx, v[j]);
  #pragma unroll
  for (int m = 1; m <= 32; m <<= 1) mx = fmaxf(mx, __shfl_xor(mx, m, 64));

  float lo = mx - 1.0f, hi = mx;
  for (int it = 0; it < 12; ++it) {
    float tau = 0.5f * (lo + hi);
    float s = 0.f;
    #pragma unroll
    for (int j = 0; j < 16; ++j) s += fmaxf(v[j] - tau, 0.f);
    #pragma unroll
    for (int m = 1; m <= 32; m <<= 1) s += __shfl_xor(s, m, 64);
    if (s >= 1.f) lo = tau; else hi = tau;
  }
  float tau = lo;
  #pragma unroll
  for (int it = 0; it < 2; ++it) {
    float s = 0.f, k = 0.f;
    #pragma unroll
    for (int j = 0; j < 16; ++j) {
      bool g = v[j] > tau;
      s += g ? v[j] : 0.f;
      k += g ? 1.f : 0.f;
    }
    #pragma unroll
    for (int m = 1; m <= 32; m <<= 1) { s += __shfl_xor(s, m, 64); k += __shfl_xor(k, m, 64); }
    tau = (s - 1.f) / k;   // k >= 1 (row max stays in support)
  }

  float* o = outp + row * N_COLS + lane * 16;
  #pragma unroll
  for (int j = 0; j < 4; ++j) {
    float4 t;
    t.x = fmaxf(v[j * 4 + 0] - tau, 0.f);
    t.y = fmaxf(v[j * 4 + 1] - tau, 0.f);
    t.z = fmaxf(v[j * 4 + 2] - tau, 0.f);
    t.w = fmaxf(v[j * 4 + 3] - tau, 0.f);
    *(float4*)(o + j * 4) = t;
  }
}

// ---------------- sparsemax in place on f32 z (mid path) ----------------
__global__ __launch_bounds__(256) void sparsemax_rows(float* __restrict__ z)
{
  const int lane = threadIdx.x & 63, wid = threadIdx.x >> 6;
  const size_t row = (size_t)blockIdx.x * 4 + wid;
  float* p = z + row * N_COLS;
  float v[16];
  #pragma unroll
  for (int j = 0; j < 4; ++j) {
    float4 t = *(const float4*)(p + j * 256 + lane * 4);
    v[j * 4 + 0] = t.x; v[j * 4 + 1] = t.y; v[j * 4 + 2] = t.z; v[j * 4 + 3] = t.w;
  }
  float mx = v[0];
  #pragma unroll
  for (int j = 1; j < 16; ++j) mx = fmaxf(mx, v[j]);
  #pragma unroll
  for (int m = 1; m <= 32; m <<= 1) mx = fmaxf(mx, __shfl_xor(mx, m, 64));
  float lo = mx - 1.0f, hi = mx;
  for (int it = 0; it < 12; ++it) {
    float tau = 0.5f * (lo + hi);
    float s = 0.f;
    #pragma unroll
    for (int j = 0; j < 16; ++j) s += fmaxf(v[j] - tau, 0.f);
    #pragma unroll
    for (int m = 1; m <= 32; m <<= 1) s += __shfl_xor(s, m, 64);
    if (s >= 1.f) lo = tau; else hi = tau;
  }
  float tau = lo;
  #pragma unroll
  for (int it = 0; it < 2; ++it) {
    float s = 0.f, k = 0.f;
    #pragma unroll
    for (int j = 0; j < 16; ++j) {
      bool g = v[j] > tau;
      s += g ? v[j] : 0.f;
      k += g ? 1.f : 0.f;
    }
    #pragma unroll
    for (int m = 1; m <= 32; m <<= 1) { s += __shfl_xor(s, m, 64); k += __shfl_xor(k, m, 64); }
    tau = (s - 1.f) / k;
  }
  #pragma unroll
  for (int j = 0; j < 4; ++j) {
    float4 t;
    t.x = fmaxf(v[j * 4 + 0] - tau, 0.f);
    t.y = fmaxf(v[j * 4 + 1] - tau, 0.f);
    t.z = fmaxf(v[j * 4 + 2] - tau, 0.f);
    t.w = fmaxf(v[j * 4 + 3] - tau, 0.f);
    *(float4*)(p + j * 256 + lane * 4) = t;
  }
}

// ---------------- FALLBACK GEMM (tiny ws): A reg-staged fp32->f16, dbuf ----------------
__global__ __launch_bounds__(256, 2) void gemm_f16(
    const float* __restrict__ A, const _Float16* __restrict__ Wt,
    const float* __restrict__ bias, const float* __restrict__ priors,
    float* __restrict__ out)
{
  __shared__ char smem[65536];
  const int tid = threadIdx.x;
  const int lane = tid & 63, wid = tid >> 6;
  const int wm = wid >> 1, wnn = wid & 1;
  int orig = blockIdx.x;
  int wgid = (orig & 7) * 512 + (orig >> 3);
  int mb = wgid >> 3, nb = wgid & 7;
  const int m0 = mb * 128, n0 = nb * 128;
  f32x4 acc[4][4];
  #pragma unroll
  for (int i = 0; i < 4; ++i)
    #pragma unroll
    for (int j = 0; j < 4; ++j) acc[i][j] = (f32x4){0.f, 0.f, 0.f, 0.f};
  float4 areg[8];
  auto loadA = [&](int kt) {
    #pragma unroll
    for (int j = 0; j < 8; ++j) {
      int f = j * 256 + tid;
      int ml = f >> 4, k4 = (f & 15) << 2;
      areg[j] = *(const float4*)(A + (size_t)(m0 + ml) * K_DIM + kt * 64 + k4);
    }
  };
  auto storeA = [&](int buf) {
    int base = buf * 16384;
    #pragma unroll
    for (int j = 0; j < 8; ++j) {
      int f = j * 256 + tid;
      int ml = f >> 4, k4 = (f & 15) << 2;
      int off = ml * 128 + ((k4 * 2) ^ ((ml & 7) << 4));
      union { _Float16 h[4]; uint2 u; } p;
      p.h[0] = (_Float16)areg[j].x; p.h[1] = (_Float16)areg[j].y;
      p.h[2] = (_Float16)areg[j].z; p.h[3] = (_Float16)areg[j].w;
      *(uint2*)(&smem[base + off]) = p.u;
    }
  };
  auto issueB = [&](int kt, int buf) {
    int base = 32768 + buf * 16384;
    #pragma unroll
    for (int t4 = 0; t4 < 4; ++t4) {
      int ch = t4 * 256 + tid;
      int nl = ch >> 3, c = ch & 7;
      const char* src = (const char*)Wt + ((size_t)(n0 + nl) * K_DIM + kt * 64) * 2
          + ((c * 16) ^ ((nl & 7) << 4));
      __builtin_amdgcn_global_load_lds(
          (const __attribute__((address_space(1))) unsigned int*)src,
          (__attribute__((address_space(3))) unsigned int*)(&smem[base + ch * 16]),
          16, 0, 0);
    }
  };
  loadA(0); issueB(0, 0); storeA(0);
  __syncthreads();
  for (int kt = 0; kt < 16; ++kt) {
    int curb = kt & 1, nxt = curb ^ 1;
    if (kt < 15) { loadA(kt + 1); issueB(kt + 1, nxt); }
    int ab = curb * 16384, bb = 32768 + curb * 16384;
    #pragma unroll
    for (int kc = 0; kc < 2; ++kc) {
      int k2 = (kc * 32 + ((lane >> 4) * 8)) * 2;
      f16x8 af[4], bfr[4];
      #pragma unroll
      for (int fm = 0; fm < 4; ++fm) {
        int rl2 = wm * 64 + fm * 16 + (lane & 15);
        af[fm] = *(const f16x8*)(&smem[ab + rl2 * 128 + (k2 ^ ((rl2 & 7) << 4))]);
      }
      #pragma unroll
      for (int fn = 0; fn < 4; ++fn) {
        int nl = wnn * 64 + fn * 16 + (lane & 15);
        bfr[fn] = *(const f16x8*)(&smem[bb + nl * 128 + (k2 ^ ((nl & 7) << 4))]);
      }
      #pragma unroll
      for (int fm = 0; fm < 4; ++fm)
        #pragma unroll
        for (int fn = 0; fn < 4; ++fn)
          acc[fm][fn] = __builtin_amdgcn_mfma_f32_16x16x32_f16(af[fm], bfr[fn], acc[fm][fn], 0, 0, 0);
    }
    if (kt < 15) storeA(nxt);
    __syncthreads();
  }
  #pragma unroll
  for (int fn = 0; fn < 4; ++fn) {
    int col = n0 + wnn * 64 + fn * 16 + (lane & 15);
    float bvv = bias[col];
    #pragma unroll
    for (int fm = 0; fm < 4; ++fm) {
      int row0 = m0 + wm * 64 + fm * 16 + ((lane >> 4) << 2);
      #pragma unroll
      for (int r = 0; r < 4; ++r) {
        size_t idx = (size_t)(row0 + r) * N_COLS + col;
        out[idx] = (acc[fm][fn][r] + bvv) * priors[idx];
      }
    }
  }
}

// ---------------- launch ----------------
extern "C" void kernel_launch(void* const* d_in, const int* in_sizes, int n_in,
                              void* d_out, int out_size, void* d_ws, size_t ws_size,
                              hipStream_t stream) {
  const float* inputs = (const float*)d_in[0];
  const float* priors = (const float*)d_in[1];
  const float* W      = (const float*)d_in[2];
  const float* gamma  = (const float*)d_in[3];
  const float* beta   = (const float*)d_in[4];
  const float* mean   = (const float*)d_in[5];
  const float* var    = (const float*)d_in[6];
  float* out = (float*)d_out;

  char* ws = (char*)d_ws;
  float* bias  = (float*)ws;                 // 4 KB
  float* scale = (float*)(ws + 4096);        // 4 KB
  _Float16* Wt = (_Float16*)(ws + 8192);     // 2 MB, [N][K] transposed+scaled
  const size_t AF_OFF = 8192 + (size_t)N_COLS * K_DIM * 2;          // 2105344
  _Float16* Af = (_Float16*)(ws + AF_OFF);   // 134 MB, [M][K] f16
  const size_t ZH_OFF = AF_OFF + (size_t)M_ROWS * K_DIM * 2;        // 136323072
  _Float16* zh = (_Float16*)(ws + ZH_OFF);   // 134 MB, [M][N] f16 z
  const size_t need  = ZH_OFF;                                      // Af path
  const size_t need2 = ZH_OFF + (size_t)M_ROWS * N_COLS * 2;        // + zh

  prep_scale_bias<<<4, 256, 0, stream>>>(gamma, beta, mean, var, bias, scale);
  prep_wt<<<dim3(16, 16), 256, 0, stream>>>(W, scale, Wt);

  if (ws_size >= need2) {
    conv_a_f16<<<2048, 256, 0, stream>>>(inputs, Af);
    gemm_cnt<1><<<4096, 256, 0, stream>>>(Af, Wt, bias, priors, zh);
    sparsemax_rows_h<<<16384, 256, 0, stream>>>(zh, out);
  } else if (ws_size >= need) {
    conv_a_f16<<<2048, 256, 0, stream>>>(inputs, Af);
    gemm_cnt<0><<<4096, 256, 0, stream>>>(Af, Wt, bias, priors, out);
    sparsemax_rows<<<16384, 256, 0, stream>>>(out);
  } else {
    gemm_f16<<<4096, 256, 0, stream>>>(inputs, Wt, bias, priors, out);
    sparsemax_rows<<<16384, 256, 0, stream>>>(out);
  }
}

// Round 11
// 408.004 us; speedup vs baseline: 2.2093x; 1.0080x over previous
//
#include <hip/hip_runtime.h>
#include <cstdint>
#include <cstddef>

#define M_ROWS 65536
#define N_COLS 1024
#define K_DIM  1024

typedef _Float16 f16x8 __attribute__((ext_vector_type(8)));
typedef float f32x4 __attribute__((ext_vector_type(4)));

// ---------------- prep: scale/bias ----------------
__global__ __launch_bounds__(256) void prep_scale_bias(
    const float* __restrict__ gamma, const float* __restrict__ beta,
    const float* __restrict__ mean, const float* __restrict__ var,
    float* __restrict__ bias, float* __restrict__ scale)
{
  int i = blockIdx.x * 256 + threadIdx.x;
  if (i < N_COLS) {
    float s = gamma[i] * rsqrtf(var[i] + 1e-3f);
    scale[i] = s;
    bias[i] = beta[i] - mean[i] * s;
  }
}

// ---------------- prep: W -> Wt (transposed, scaled, f16) ----------------
__global__ __launch_bounds__(256) void prep_wt(
    const float* __restrict__ W, const float* __restrict__ scale,
    _Float16* __restrict__ Wt)
{
  __shared__ float tile[64][68];
  int k0 = blockIdx.x * 64, n0 = blockIdx.y * 64;
  int t = threadIdx.x;
  int kr = t >> 2, q = t & 3;
  #pragma unroll
  for (int j = 0; j < 4; ++j) {
    float4 v = *(const float4*)(W + (size_t)(k0 + kr) * N_COLS + n0 + q * 16 + j * 4);
    *(float4*)(&tile[kr][q * 16 + j * 4]) = v;
  }
  __syncthreads();
  int nr = t >> 2;
  float sn = scale[n0 + nr];
  __align__(16) _Float16 h[16];
  #pragma unroll
  for (int j = 0; j < 16; ++j)
    h[j] = (_Float16)(tile[q * 16 + j][nr] * sn);
  uint4* dst = (uint4*)(Wt + (size_t)(n0 + nr) * K_DIM + k0 + q * 16);
  dst[0] = *(uint4*)(&h[0]);
  dst[1] = *(uint4*)(&h[8]);
}

// ---------------- prep: A (fp32) -> Af (f16), grid-stride, vectorized ----------------
__global__ __launch_bounds__(256) void conv_a_f16(
    const float* __restrict__ A, _Float16* __restrict__ Af)
{
  const size_t total8 = (size_t)M_ROWS * K_DIM / 8;
  size_t i = (size_t)blockIdx.x * 256 + threadIdx.x;
  const size_t stride = (size_t)gridDim.x * 256;
  for (; i < total8; i += stride) {
    float4 a = *(const float4*)(A + i * 8);
    float4 b = *(const float4*)(A + i * 8 + 4);
    union { _Float16 h[8]; uint4 u; } p;
    p.h[0] = (_Float16)a.x; p.h[1] = (_Float16)a.y;
    p.h[2] = (_Float16)a.z; p.h[3] = (_Float16)a.w;
    p.h[4] = (_Float16)b.x; p.h[5] = (_Float16)b.y;
    p.h[6] = (_Float16)b.z; p.h[7] = (_Float16)b.w;
    *(uint4*)(Af + i * 8) = p.u;
  }
}

// ---------------- 256x256 8-wave GEMM (m201-geometry), f16, counted pipeline ----------------
// 512 threads = 8 waves (2M x 4N); per wave 128x64 output, acc[8][4] (128 VGPR).
// LDS 128 KB: dbuf x (A 32KB + B 32KB), m97-proven row-major 128B rows + XOR swizzle.
// Wave-split staging: each wave stages its own 32 A-rows + 32 B-cols (8 loads) for
// ktile t+1, issued in quadrants 0-1 of body t -> >= half-body latency cover; boundary
// vmcnt(0) is then cheap. 2 barriers per ktile; 64 MFMA/wave between barrier pairs.
template<int F16OUT>
__global__ __launch_bounds__(512, 2) void gemm_256(
    const _Float16* __restrict__ Af, const _Float16* __restrict__ Wt,
    const float* __restrict__ bias, const float* __restrict__ priors,
    void* __restrict__ zout)
{
  __shared__ char smem[131072];   // buf b: A @ b*65536, B @ b*65536+32768
  const int tid = threadIdx.x;
  const int lane = tid & 63, wid = tid >> 6;
  const int wm = wid >> 2, wn = wid & 3;
  const int li = lane & 15, g = lane >> 4;

  // bijective XCD swizzle (nwg=1024, 1024%8==0)
  int orig = blockIdx.x;
  int wgid = (orig & 7) * 128 + (orig >> 3);
  int mb = wgid >> 2, nb = wgid & 3;
  const int m0 = mb * 256, n0 = nb * 256;

  f32x4 acc[8][4];
  #pragma unroll
  for (int i = 0; i < 8; ++i)
    #pragma unroll
    for (int j = 0; j < 4; ++j) acc[i][j] = (f32x4){0.f, 0.f, 0.f, 0.f};

  // wave-split staging shares
  const int arow0 = wm * 128 + wn * 32;                 // my 32 A-rows (local)
  const int bcol0 = (wn >> 1) * 128 + (wm * 2 + (wn & 1)) * 32;  // my 32 B-cols (local)

  auto stageA = [&](int kt, int buf) {
    #pragma unroll
    for (int j = 0; j < 4; ++j) {
      int ch = j * 64 + lane;            // 256 chunks: 32 rows x 8
      int rloc = ch >> 3, c = ch & 7;
      int row = arow0 + rloc;
      const char* src = (const char*)Af + ((size_t)(m0 + row) * K_DIM + kt * 64) * 2
                        + ((c * 16) ^ ((row & 7) << 4));
      __builtin_amdgcn_global_load_lds(
          (const __attribute__((address_space(1))) unsigned int*)src,
          (__attribute__((address_space(3))) unsigned int*)(&smem[buf * 65536 + arow0 * 128 + ch * 16]),
          16, 0, 0);
    }
  };
  auto stageB = [&](int kt, int buf) {
    #pragma unroll
    for (int j = 0; j < 4; ++j) {
      int ch = j * 64 + lane;
      int rloc = ch >> 3, c = ch & 7;
      int col = bcol0 + rloc;
      const char* src = (const char*)Wt + ((size_t)(n0 + col) * K_DIM + kt * 64) * 2
                        + ((c * 16) ^ ((col & 7) << 4));
      __builtin_amdgcn_global_load_lds(
          (const __attribute__((address_space(1))) unsigned int*)src,
          (__attribute__((address_space(3))) unsigned int*)(&smem[buf * 65536 + 32768 + bcol0 * 128 + ch * 16]),
          16, 0, 0);
    }
  };

  const int aswz = (li & 7) << 4;

  // prologue: stage ktile 0 into buf 0
  stageA(0, 0);
  stageB(0, 0);

  for (int t = 0; t < 16; ++t) {
    asm volatile("s_waitcnt vmcnt(0)" ::: "memory");   // my stage loads for ktile t landed
    __builtin_amdgcn_s_barrier();                      // everyone's landed
    asm volatile("" ::: "memory");
    __builtin_amdgcn_sched_barrier(0);

    const int cur = t & 1;
    const int abase = cur * 65536, bbase = cur * 65536 + 32768;
    const int ktn = (t + 1 < 16) ? t + 1 : 15;         // clamped (redundant tail stage harmless)

    #pragma unroll
    for (int q = 0; q < 4; ++q) {
      if (q == 0) stageA(ktn, cur ^ 1);                // early issue -> latency cover
      if (q == 1) stageB(ktn, cur ^ 1);
      const int qr = q >> 1, qc = q & 1;
      f16x8 af[4][2], bf[2][2];
      #pragma unroll
      for (int kc = 0; kc < 2; ++kc) {
        const int koff = (kc * 64 + g * 16) ^ aswz;
        #pragma unroll
        for (int fr = 0; fr < 4; ++fr) {
          int row = wm * 128 + qr * 64 + fr * 16 + li;
          af[fr][kc] = *(const f16x8*)(&smem[abase + row * 128 + koff]);
        }
        #pragma unroll
        for (int fc = 0; fc < 2; ++fc) {
          int col = wn * 64 + qc * 32 + fc * 16 + li;
          bf[fc][kc] = *(const f16x8*)(&smem[bbase + col * 128 + koff]);
        }
      }
      __builtin_amdgcn_s_setprio(1);
      #pragma unroll
      for (int kc = 0; kc < 2; ++kc)
        #pragma unroll
        for (int fr = 0; fr < 4; ++fr)
          #pragma unroll
          for (int fc = 0; fc < 2; ++fc)
            acc[qr * 4 + fr][qc * 2 + fc] = __builtin_amdgcn_mfma_f32_16x16x32_f16(
                af[fr][kc], bf[fc][kc], acc[qr * 4 + fr][qc * 2 + fc], 0, 0, 0);
      __builtin_amdgcn_s_setprio(0);
    }

    asm volatile("s_waitcnt lgkmcnt(0)" ::: "memory"); // my LDS reads retired
    __builtin_amdgcn_s_barrier();                      // buf[cur] free for restage
    asm volatile("" ::: "memory");
    __builtin_amdgcn_sched_barrier(0);
  }

  // epilogue: z = (acc + bias) * priors -> f16 zh (or f32)
  // row = m0 + wm*128 + i*16 + g*4 + r ; col = n0 + wn*64 + j*16 + li
  float bv[4];
  #pragma unroll
  for (int j = 0; j < 4; ++j) bv[j] = bias[n0 + wn * 64 + j * 16 + li];
  #pragma unroll
  for (int i = 0; i < 8; ++i) {
    #pragma unroll
    for (int r = 0; r < 4; ++r) {
      size_t row = (size_t)(m0 + wm * 128 + i * 16 + g * 4 + r);
      const float* pp = priors + row * N_COLS + n0 + wn * 64 + li;
      #pragma unroll
      for (int j = 0; j < 4; ++j) {
        float z = (acc[i][j][r] + bv[j]) * pp[j * 16];
        size_t idx = row * N_COLS + n0 + wn * 64 + j * 16 + li;
        if (F16OUT) ((_Float16*)zout)[idx] = (_Float16)z;
        else        ((float*)zout)[idx] = z;
      }
    }
  }
}

// ---------------- sparsemax from f16 z -> f32 out, one wave per row ----------------
__global__ __launch_bounds__(256) void sparsemax_rows_h(
    const _Float16* __restrict__ zh, float* __restrict__ outp)
{
  const int lane = threadIdx.x & 63, wid = threadIdx.x >> 6;
  const size_t row = (size_t)blockIdx.x * 4 + wid;
  const _Float16* p = zh + row * N_COLS + lane * 16;

  f16x8 h0 = *(const f16x8*)(p);
  f16x8 h1 = *(const f16x8*)(p + 8);
  float v[16];
  #pragma unroll
  for (int j = 0; j < 8; ++j) { v[j] = (float)h0[j]; v[8 + j] = (float)h1[j]; }

  float mx = v[0];
  #pragma unroll
  for (int j = 1; j < 16; ++j) mx = fmaxf(mx, v[j]);
  #pragma unroll
  for (int m = 1; m <= 32; m <<= 1) mx = fmaxf(mx, __shfl_xor(mx, m, 64));

  float lo = mx - 1.0f, hi = mx;
  for (int it = 0; it < 12; ++it) {
    float tau = 0.5f * (lo + hi);
    float s = 0.f;
    #pragma unroll
    for (int j = 0; j < 16; ++j) s += fmaxf(v[j] - tau, 0.f);
    #pragma unroll
    for (int m = 1; m <= 32; m <<= 1) s += __shfl_xor(s, m, 64);
    if (s >= 1.f) lo = tau; else hi = tau;
  }
  float tau = lo;
  #pragma unroll
  for (int it = 0; it < 2; ++it) {
    float s = 0.f, k = 0.f;
    #pragma unroll
    for (int j = 0; j < 16; ++j) {
      bool g = v[j] > tau;
      s += g ? v[j] : 0.f;
      k += g ? 1.f : 0.f;
    }
    #pragma unroll
    for (int m = 1; m <= 32; m <<= 1) { s += __shfl_xor(s, m, 64); k += __shfl_xor(k, m, 64); }
    tau = (s - 1.f) / k;   // k >= 1 (row max stays in support)
  }

  float* o = outp + row * N_COLS + lane * 16;
  #pragma unroll
  for (int j = 0; j < 4; ++j) {
    float4 t;
    t.x = fmaxf(v[j * 4 + 0] - tau, 0.f);
    t.y = fmaxf(v[j * 4 + 1] - tau, 0.f);
    t.z = fmaxf(v[j * 4 + 2] - tau, 0.f);
    t.w = fmaxf(v[j * 4 + 3] - tau, 0.f);
    *(float4*)(o + j * 4) = t;
  }
}

// ---------------- sparsemax in place on f32 z (mid path) ----------------
__global__ __launch_bounds__(256) void sparsemax_rows(float* __restrict__ z)
{
  const int lane = threadIdx.x & 63, wid = threadIdx.x >> 6;
  const size_t row = (size_t)blockIdx.x * 4 + wid;
  float* p = z + row * N_COLS;
  float v[16];
  #pragma unroll
  for (int j = 0; j < 4; ++j) {
    float4 t = *(const float4*)(p + j * 256 + lane * 4);
    v[j * 4 + 0] = t.x; v[j * 4 + 1] = t.y; v[j * 4 + 2] = t.z; v[j * 4 + 3] = t.w;
  }
  float mx = v[0];
  #pragma unroll
  for (int j = 1; j < 16; ++j) mx = fmaxf(mx, v[j]);
  #pragma unroll
  for (int m = 1; m <= 32; m <<= 1) mx = fmaxf(mx, __shfl_xor(mx, m, 64));
  float lo = mx - 1.0f, hi = mx;
  for (int it = 0; it < 12; ++it) {
    float tau = 0.5f * (lo + hi);
    float s = 0.f;
    #pragma unroll
    for (int j = 0; j < 16; ++j) s += fmaxf(v[j] - tau, 0.f);
    #pragma unroll
    for (int m = 1; m <= 32; m <<= 1) s += __shfl_xor(s, m, 64);
    if (s >= 1.f) lo = tau; else hi = tau;
  }
  float tau = lo;
  #pragma unroll
  for (int it = 0; it < 2; ++it) {
    float s = 0.f, k = 0.f;
    #pragma unroll
    for (int j = 0; j < 16; ++j) {
      bool g = v[j] > tau;
      s += g ? v[j] : 0.f;
      k += g ? 1.f : 0.f;
    }
    #pragma unroll
    for (int m = 1; m <= 32; m <<= 1) { s += __shfl_xor(s, m, 64); k += __shfl_xor(k, m, 64); }
    tau = (s - 1.f) / k;
  }
  #pragma unroll
  for (int j = 0; j < 4; ++j) {
    float4 t;
    t.x = fmaxf(v[j * 4 + 0] - tau, 0.f);
    t.y = fmaxf(v[j * 4 + 1] - tau, 0.f);
    t.z = fmaxf(v[j * 4 + 2] - tau, 0.f);
    t.w = fmaxf(v[j * 4 + 3] - tau, 0.f);
    *(float4*)(p + j * 256 + lane * 4) = t;
  }
}

// ---------------- FALLBACK GEMM (tiny ws): A reg-staged fp32->f16, dbuf ----------------
__global__ __launch_bounds__(256, 2) void gemm_f16(
    const float* __restrict__ A, const _Float16* __restrict__ Wt,
    const float* __restrict__ bias, const float* __restrict__ priors,
    float* __restrict__ out)
{
  __shared__ char smem[65536];
  const int tid = threadIdx.x;
  const int lane = tid & 63, wid = tid >> 6;
  const int wm = wid >> 1, wnn = wid & 1;
  int orig = blockIdx.x;
  int wgid = (orig & 7) * 512 + (orig >> 3);
  int mb = wgid >> 3, nb = wgid & 7;
  const int m0 = mb * 128, n0 = nb * 128;
  f32x4 acc[4][4];
  #pragma unroll
  for (int i = 0; i < 4; ++i)
    #pragma unroll
    for (int j = 0; j < 4; ++j) acc[i][j] = (f32x4){0.f, 0.f, 0.f, 0.f};
  float4 areg[8];
  auto loadA = [&](int kt) {
    #pragma unroll
    for (int j = 0; j < 8; ++j) {
      int f = j * 256 + tid;
      int ml = f >> 4, k4 = (f & 15) << 2;
      areg[j] = *(const float4*)(A + (size_t)(m0 + ml) * K_DIM + kt * 64 + k4);
    }
  };
  auto storeA = [&](int buf) {
    int base = buf * 16384;
    #pragma unroll
    for (int j = 0; j < 8; ++j) {
      int f = j * 256 + tid;
      int ml = f >> 4, k4 = (f & 15) << 2;
      int off = ml * 128 + ((k4 * 2) ^ ((ml & 7) << 4));
      union { _Float16 h[4]; uint2 u; } p;
      p.h[0] = (_Float16)areg[j].x; p.h[1] = (_Float16)areg[j].y;
      p.h[2] = (_Float16)areg[j].z; p.h[3] = (_Float16)areg[j].w;
      *(uint2*)(&smem[base + off]) = p.u;
    }
  };
  auto issueB = [&](int kt, int buf) {
    int base = 32768 + buf * 16384;
    #pragma unroll
    for (int t4 = 0; t4 < 4; ++t4) {
      int ch = t4 * 256 + tid;
      int nl = ch >> 3, c = ch & 7;
      const char* src = (const char*)Wt + ((size_t)(n0 + nl) * K_DIM + kt * 64) * 2
          + ((c * 16) ^ ((nl & 7) << 4));
      __builtin_amdgcn_global_load_lds(
          (const __attribute__((address_space(1))) unsigned int*)src,
          (__attribute__((address_space(3))) unsigned int*)(&smem[base + ch * 16]),
          16, 0, 0);
    }
  };
  loadA(0); issueB(0, 0); storeA(0);
  __syncthreads();
  for (int kt = 0; kt < 16; ++kt) {
    int curb = kt & 1, nxt = curb ^ 1;
    if (kt < 15) { loadA(kt + 1); issueB(kt + 1, nxt); }
    int ab = curb * 16384, bb = 32768 + curb * 16384;
    #pragma unroll
    for (int kc = 0; kc < 2; ++kc) {
      int k2 = (kc * 32 + ((lane >> 4) * 8)) * 2;
      f16x8 af[4], bfr[4];
      #pragma unroll
      for (int fm = 0; fm < 4; ++fm) {
        int rl2 = wm * 64 + fm * 16 + (lane & 15);
        af[fm] = *(const f16x8*)(&smem[ab + rl2 * 128 + (k2 ^ ((rl2 & 7) << 4))]);
      }
      #pragma unroll
      for (int fn = 0; fn < 4; ++fn) {
        int nl = wnn * 64 + fn * 16 + (lane & 15);
        bfr[fn] = *(const f16x8*)(&smem[bb + nl * 128 + (k2 ^ ((nl & 7) << 4))]);
      }
      #pragma unroll
      for (int fm = 0; fm < 4; ++fm)
        #pragma unroll
        for (int fn = 0; fn < 4; ++fn)
          acc[fm][fn] = __builtin_amdgcn_mfma_f32_16x16x32_f16(af[fm], bfr[fn], acc[fm][fn], 0, 0, 0);
    }
    if (kt < 15) storeA(nxt);
    __syncthreads();
  }
  #pragma unroll
  for (int fn = 0; fn < 4; ++fn) {
    int col = n0 + wnn * 64 + fn * 16 + (lane & 15);
    float bvv = bias[col];
    #pragma unroll
    for (int fm = 0; fm < 4; ++fm) {
      int row0 = m0 + wm * 64 + fm * 16 + ((lane >> 4) << 2);
      #pragma unroll
      for (int r = 0; r < 4; ++r) {
        size_t idx = (size_t)(row0 + r) * N_COLS + col;
        out[idx] = (acc[fm][fn][r] + bvv) * priors[idx];
      }
    }
  }
}

// ---------------- launch ----------------
extern "C" void kernel_launch(void* const* d_in, const int* in_sizes, int n_in,
                              void* d_out, int out_size, void* d_ws, size_t ws_size,
                              hipStream_t stream) {
  const float* inputs = (const float*)d_in[0];
  const float* priors = (const float*)d_in[1];
  const float* W      = (const float*)d_in[2];
  const float* gamma  = (const float*)d_in[3];
  const float* beta   = (const float*)d_in[4];
  const float* mean   = (const float*)d_in[5];
  const float* var    = (const float*)d_in[6];
  float* out = (float*)d_out;

  char* ws = (char*)d_ws;
  float* bias  = (float*)ws;                 // 4 KB
  float* scale = (float*)(ws + 4096);        // 4 KB
  _Float16* Wt = (_Float16*)(ws + 8192);     // 2 MB, [N][K] transposed+scaled
  const size_t AF_OFF = 8192 + (size_t)N_COLS * K_DIM * 2;          // 2105344
  _Float16* Af = (_Float16*)(ws + AF_OFF);   // 134 MB, [M][K] f16
  const size_t ZH_OFF = AF_OFF + (size_t)M_ROWS * K_DIM * 2;        // 136323072
  _Float16* zh = (_Float16*)(ws + ZH_OFF);   // 134 MB, [M][N] f16 z
  const size_t need  = ZH_OFF;
  const size_t need2 = ZH_OFF + (size_t)M_ROWS * N_COLS * 2;

  prep_scale_bias<<<4, 256, 0, stream>>>(gamma, beta, mean, var, bias, scale);
  prep_wt<<<dim3(16, 16), 256, 0, stream>>>(W, scale, Wt);

  if (ws_size >= need2) {
    conv_a_f16<<<2048, 256, 0, stream>>>(inputs, Af);
    gemm_256<1><<<1024, 512, 0, stream>>>(Af, Wt, bias, priors, zh);
    sparsemax_rows_h<<<16384, 256, 0, stream>>>(zh, out);
  } else if (ws_size >= need) {
    conv_a_f16<<<2048, 256, 0, stream>>>(inputs, Af);
    gemm_256<0><<<1024, 512, 0, stream>>>(Af, Wt, bias, priors, out);
    sparsemax_rows<<<16384, 256, 0, stream>>>(out);
  } else {
    gemm_f16<<<4096, 256, 0, stream>>>(inputs, Wt, bias, priors, out);
    sparsemax_rows<<<16384, 256, 0, stream>>>(out);
  }
}